// Round 6
// baseline (482.435 us; speedup 1.0000x reference)
//
#include <hip/hip_runtime.h>

// LSTM: B=2048 independent sequences, T=2048 serial steps, H=16, IN=1.
// R6: TWO batch elements per wave (1024 waves = 1/SIMD), software-interleaved
// instruction-by-instruction so the two independent recurrence chains hide
// each other's bpermute/trans latency deterministically (R5 showed 2 HW waves
// phase-lock: wall 425 cyc/step vs ideal ~300). Lane l = gate row l
// (i:0-15, f:16-31, g:32-47, o:48-63); w[16] SHARED between the two chains.
// Matvec: fused v_fmac_f32_dpp row_ror vs pre-rotated pre-scaled W_hh
// (2 chains of 8 per batch = 4 independent chains interleaved).
// Gather: 4x ds_bpermute per chain. Folds: w/wih/bias pre-scaled by mco;
// c scaled by -2log2e; h = fmaf(2o, r2, -o) kills the dependent mul.

__device__ __forceinline__ float i2f(int i) { return __int_as_float(i); }
__device__ __forceinline__ int   f2i(float f) { return __float_as_int(f); }

#define LOG2E 1.44269504088896340736f

// Fused rotate+FMA: acc += h[(j +- n) & 15] * w   (one VALU instruction)
#define FMAC_DPP(acc, h_, w_, n)                                               \
    asm("v_fmac_f32_dpp %0, %1, %2 row_ror:" #n " row_mask:0xf bank_mask:0xf"  \
        : "+v"(acc) : "v"(h_), "v"(w_));
#define MUL_DPP(dst, h_, w_, n)                                                \
    asm("v_mul_f32_dpp %0, %1, %2 row_ror:" #n " row_mask:0xf bank_mask:0xf"   \
        : "=v"(dst) : "v"(h_), "v"(w_));

#define STEP2(s_expr) {                                                      \
    float xsA_ = i2f(__builtin_amdgcn_readlane(f2i(xblkA), (s_expr)));       \
    float xsB_ = i2f(__builtin_amdgcn_readlane(f2i(xblkB), (s_expr)));       \
    float aAl_ = fmaf(wih_s, xsA_, bias_s);                                  \
    float aBl_ = fmaf(wih_s, xsB_, bias_s);                                  \
    float aAh_, aBh_;                                                        \
    aAl_ = fmaf(hA, w[0], aAl_);                                             \
    aBl_ = fmaf(hB, w[0], aBl_);                                             \
    MUL_DPP(aAh_, hA, w[8], 8)    MUL_DPP(aBh_, hB, w[8], 8)                 \
    FMAC_DPP(aAl_, hA, w[1], 1)   FMAC_DPP(aBl_, hB, w[1], 1)                \
    FMAC_DPP(aAh_, hA, w[9], 9)   FMAC_DPP(aBh_, hB, w[9], 9)                \
    FMAC_DPP(aAl_, hA, w[2], 2)   FMAC_DPP(aBl_, hB, w[2], 2)                \
    FMAC_DPP(aAh_, hA, w[10],10)  FMAC_DPP(aBh_, hB, w[10],10)               \
    FMAC_DPP(aAl_, hA, w[3], 3)   FMAC_DPP(aBl_, hB, w[3], 3)                \
    FMAC_DPP(aAh_, hA, w[11],11)  FMAC_DPP(aBh_, hB, w[11],11)               \
    FMAC_DPP(aAl_, hA, w[4], 4)   FMAC_DPP(aBl_, hB, w[4], 4)                \
    FMAC_DPP(aAh_, hA, w[12],12)  FMAC_DPP(aBh_, hB, w[12],12)               \
    FMAC_DPP(aAl_, hA, w[5], 5)   FMAC_DPP(aBl_, hB, w[5], 5)                \
    FMAC_DPP(aAh_, hA, w[13],13)  FMAC_DPP(aBh_, hB, w[13],13)               \
    FMAC_DPP(aAl_, hA, w[6], 6)   FMAC_DPP(aBl_, hB, w[6], 6)                \
    FMAC_DPP(aAh_, hA, w[14],14)  FMAC_DPP(aBh_, hB, w[14],14)               \
    FMAC_DPP(aAl_, hA, w[7], 7)   FMAC_DPP(aBl_, hB, w[7], 7)                \
    FMAC_DPP(aAh_, hA, w[15],15)  FMAC_DPP(aBh_, hB, w[15],15)               \
    float accA_ = aAl_ + aAh_;                                               \
    float accB_ = aBl_ + aBh_;                                               \
    float eA_ = __builtin_amdgcn_exp2f(accA_);      /* pre-scaled */         \
    float eB_ = __builtin_amdgcn_exp2f(accB_);                               \
    float rA_ = __builtin_amdgcn_rcpf(1.0f + eA_);                           \
    float rB_ = __builtin_amdgcn_rcpf(1.0f + eB_);                           \
    float actA_ = fmaf(aco, rA_, bco);                                       \
    float actB_ = fmaf(aco, rB_, bco);                                       \
    int aiA_ = f2i(actA_); int aiB_ = f2i(actB_);                            \
    float giA_ = i2f(__builtin_amdgcn_ds_bpermute(addr_i, aiA_));            \
    float giB_ = i2f(__builtin_amdgcn_ds_bpermute(addr_i, aiB_));            \
    float gfA_ = i2f(__builtin_amdgcn_ds_bpermute(addr_f, aiA_));            \
    float gfB_ = i2f(__builtin_amdgcn_ds_bpermute(addr_f, aiB_));            \
    float ggA_ = i2f(__builtin_amdgcn_ds_bpermute(addr_g, aiA_));            \
    float ggB_ = i2f(__builtin_amdgcn_ds_bpermute(addr_g, aiB_));            \
    float goA_ = i2f(__builtin_amdgcn_ds_bpermute(addr_o, aiA_));            \
    float goB_ = i2f(__builtin_amdgcn_ds_bpermute(addr_o, aiB_));            \
    cA = fmaf(gfA_, cA, giA_ * ggA_);   /* c scaled by -2log2e */            \
    cB = fmaf(gfB_, cB, giB_ * ggB_);                                        \
    float o2A_ = goA_ + goA_;           /* off-chain */                      \
    float o2B_ = goB_ + goB_;                                                \
    float e2A_ = __builtin_amdgcn_exp2f(cA);                                 \
    float e2B_ = __builtin_amdgcn_exp2f(cB);                                 \
    float r2A_ = __builtin_amdgcn_rcpf(1.0f + e2A_);                         \
    float r2B_ = __builtin_amdgcn_rcpf(1.0f + e2B_);                         \
    hA = fmaf(o2A_, r2A_, -goA_);       /* o*(2*r2-1) = o*tanh(c) */         \
    hB = fmaf(o2B_, r2B_, -goB_);                                            \
}

__global__ __launch_bounds__(256)
void lstm_fused(
    const float* __restrict__ x,
    const float* __restrict__ Wih,
    const float* __restrict__ Whh,
    const float* __restrict__ bih,
    const float* __restrict__ bhh,
    const float* __restrict__ Wfc,
    const float* __restrict__ bfc,
    float* __restrict__ out)
{
    const int T   = 2048;
    const int wid = (blockIdx.x * blockDim.x + threadIdx.x) >> 6;
    const int b0  = wid * 2;             // two batch elements per wave
    const int b1  = b0 + 1;
    const int l   = threadIdx.x & 63;    // gate row
    const int j   = l & 15;              // hidden unit
    const int gate = l >> 4;             // 0:i 1:f 2:g 3:o

    // Probe DPP row_ror direction: after ror:1, lane l holds j from lane (l+-1)&15.
    int probe = __builtin_amdgcn_mov_dpp(j, 0x121, 0xF, 0xF, true);
    const int dir = (probe == ((j + 1) & 15)) ? 1 : -1;

    // sigmoid(z)=rcp(1+exp2(-log2e*z)); tanh(z)=2*rcp(1+exp2(-2log2e*z))-1
    const float mco = (gate == 2) ? (-2.0f * LOG2E) : (-LOG2E);
    // g-gate affine also folds the -2log2e scale of c:
    const float aco = (gate == 2) ? (-4.0f * LOG2E) : 1.0f;
    const float bco = (gate == 2) ? ( 2.0f * LOG2E) : 0.0f;

    // Pre-rotated + pre-scaled W_hh row: w[s] pairs with row_ror:s of h.
    // SHARED between the two chains (same weights).
    float w[16];
#pragma unroll
    for (int s = 0; s < 16; ++s) {
        int k = (j + s * dir + 32) & 15;
        w[s] = Whh[l * 16 + k] * mco;
    }

    const float wih_s  = Wih[l] * mco;            // IN = 1
    const float bias_s = (bih[l] + bhh[l]) * mco;

    // bpermute byte addresses for gathering i,f,g,o of unit j
    const int addr_i = (j     ) << 2;
    const int addr_f = (j + 16) << 2;
    const int addr_g = (j + 32) << 2;
    const int addr_o = (j + 48) << 2;

    const float* xpA = x + (size_t)b0 * T;
    const float* xpB = x + (size_t)b1 * T;
    float xblkA = xpA[l];                // 64 timesteps staged per VGPR, per chain
    float xblkB = xpB[l];

    float hA = 0.0f, cA = 0.0f;          // c holds -2log2e * c_real
    float hB = 0.0f, cB = 0.0f;

#pragma unroll 1
    for (int blk = 0; blk < 32; ++blk) {
        const int nxt = (blk < 31) ? (blk + 1) : 31;
        float xnA = xpA[nxt * 64 + l];   // prefetch next x blocks (vmcnt path)
        float xnB = xpB[nxt * 64 + l];
#pragma unroll 1
        for (int sub = 0; sub < 4; ++sub) {
            const int base = sub << 4;   // runtime readlane index is allowed
#pragma unroll
            for (int k = 0; k < 16; ++k) {
                STEP2(base + k)
            }
        }
        xblkA = xnA;
        xblkB = xnB;
    }

    // out[b] = sum_j Wfc[j]*h[j] + bfc ; h replicated 4x -> scale by 0.25
    const float wf = Wfc[j] * 0.25f;
    float pA = hA * wf;
    float pB = hB * wf;
    pA += __shfl_xor(pA, 32);  pB += __shfl_xor(pB, 32);
    pA += __shfl_xor(pA, 16);  pB += __shfl_xor(pB, 16);
    pA += __shfl_xor(pA, 8);   pB += __shfl_xor(pB, 8);
    pA += __shfl_xor(pA, 4);   pB += __shfl_xor(pB, 4);
    pA += __shfl_xor(pA, 2);   pB += __shfl_xor(pB, 2);
    pA += __shfl_xor(pA, 1);   pB += __shfl_xor(pB, 1);
    if (l == 0) {
        float bb = bfc[0];
        out[b0] = pA + bb;
        out[b1] = pB + bb;
    }
}

extern "C" void kernel_launch(void* const* d_in, const int* in_sizes, int n_in,
                              void* d_out, int out_size, void* d_ws, size_t ws_size,
                              hipStream_t stream) {
    const float* x   = (const float*)d_in[0];
    const float* Wih = (const float*)d_in[1];
    const float* Whh = (const float*)d_in[2];
    const float* bih = (const float*)d_in[3];
    const float* bhh = (const float*)d_in[4];
    const float* Wfc = (const float*)d_in[5];
    const float* bfc = (const float*)d_in[6];
    float* out = (float*)d_out;

    const int B = 2048;
    const int threads = 256;                    // 4 waves/block, 2 batches/wave
    const int blocks  = (B / 2) * 64 / threads; // 256 blocks -> 1 wave/SIMD
    hipLaunchKernelGGL(lstm_fused, dim3(blocks), dim3(threads), 0, stream,
                       x, Wih, Whh, bih, bhh, Wfc, bfc, out);
}